// Round 7
// baseline (444.463 us; speedup 1.0000x reference)
//
#include <hip/hip_runtime.h>
#include <math.h>

typedef __attribute__((ext_vector_type(8)))  short bf16x8;
typedef __attribute__((ext_vector_type(4)))  float f32x4;
typedef __attribute__((ext_vector_type(16))) float f32x16;
typedef __attribute__((ext_vector_type(2)))  float f32x2;

#define TRI(i,j) (((i)*((i)+1))/2 + (j))
#define ONE3 0.3333333333333333f
#define QOFF 6144   /* Q/R consts after 64*96B frag records */
#define LOFF 8192   /* cholesky L buffer: [batch][48] f32 (col c at c*8, 2 pad) */

// RNE f32->bf16 (moment fragments: precision matters)
static __device__ __forceinline__ unsigned short f2b(float f) {
  union { float f; unsigned u; } v; v.f = f;
  unsigned r = v.u + 0x7FFFu + ((v.u >> 16) & 1u);
  return (unsigned short)(r >> 16);
}
static __device__ __forceinline__ unsigned pk2(float lo, float hi) {
  return (unsigned)f2b(lo) | ((unsigned)f2b(hi) << 16);
}
// truncating pack (NN path, dt-damped)
static __device__ __forceinline__ unsigned pk2t(float lo, float hi) {
  return __builtin_amdgcn_perm(__float_as_uint(hi), __float_as_uint(lo), 0x07060302u);
}

// odd deg-7 tanh approx, fitted [-3,3]; no clamp (preactivations bounded, dt-damped)
#define TC0 0.970866f
#define TC1 (-0.217815f)
#define TC2 0.028904f
#define TC3 (-0.0014079f)

static __device__ __forceinline__ unsigned tanh2_pk(float a, float b) {
#if __has_builtin(__builtin_elementwise_fma)
  f32x2 z; z[0] = a; z[1] = b;
  f32x2 k3 = {TC3, TC3}, k2 = {TC2, TC2}, k1 = {TC1, TC1}, k0 = {TC0, TC0};
  f32x2 t = z * z;
  f32x2 p = __builtin_elementwise_fma(t, k3, k2);
  p = __builtin_elementwise_fma(p, t, k1);
  p = __builtin_elementwise_fma(p, t, k0);
  f32x2 r = z * p;
  return pk2t(r[0], r[1]);
#else
  float ta = a * a, tb = b * b;
  float pa = fmaf(fmaf(fmaf(TC3, ta, TC2), ta, TC1), ta, TC0);
  float pb = fmaf(fmaf(fmaf(TC3, tb, TC2), tb, TC1), tb, TC0);
  return pk2t(a * pa, b * pb);
#endif
}

// ---- prep: per-batch cholesky -> Lbuf; block 0 lanes 0..63 also pack weight frags ----
// A2 k-slot perm: hidden(kq,u,j) = 32*(kq>>1) + 16*(kq&1) + 4u + (j<4?j:j+4) so each
// lane's D1 C-layout regs Hpk[4kq..4kq+3] ARE the layer-2 B fragment (no exchange).
// A2 m-rows DUPLICATED so both u-halves own all 6 feats in d2 regs 0..5:
//   rows 0-3 = feats0-3, rows 4-7 = feats0-3, rows 8-9 = feats4-5, rows 12-13 = feats4-5.
__global__ void prep_kernel(const float* __restrict__ gP,
                            const float* __restrict__ W1, const float* __restrict__ b1,
                            const float* __restrict__ W2,
                            const float* __restrict__ LQ, const float* __restrict__ LR,
                            char* __restrict__ ws, float* __restrict__ Lbuf, int B) {
  if (blockIdx.x == 0 && threadIdx.x < 64) {
    int lane = threadIdx.x;
    int mr = lane & 31, u = lane >> 5;
    unsigned* A1 = (unsigned*)(ws + lane * 96);
    unsigned* A2 = (unsigned*)(ws + lane * 96 + 32);
#pragma unroll
    for (int t = 0; t < 2; ++t) {
      int h = 32 * t + mr;
      if (u == 0) {
#pragma unroll
        for (int p = 0; p < 4; ++p)
          A1[t * 4 + p] = pk2(W1[(2 * p) * 64 + h], W1[(2 * p + 1) * 64 + h]);
      } else {
        A1[t * 4 + 0] = pk2(b1[h], 0.0f);
        A1[t * 4 + 1] = 0u; A1[t * 4 + 2] = 0u; A1[t * 4 + 3] = 0u;
      }
    }
    int fr = (mr < 4) ? mr
           : (mr < 10) ? (mr - 4)
           : (mr >= 12 && mr < 14) ? (mr - 8) : -1;
#pragma unroll
    for (int kq = 0; kq < 4; ++kq) {
#pragma unroll
      for (int p = 0; p < 4; ++p) {
        int rm = 2 * p + ((p >= 2) ? 4 : 0);
        int hid = 32 * (kq >> 1) + 16 * (kq & 1) + 4 * u + rm;
        float lo = (fr >= 0) ? W2[hid * 6 + fr] : 0.0f;
        float hi = (fr >= 0) ? W2[(hid + 1) * 6 + fr] : 0.0f;
        A2[kq * 4 + p] = pk2(lo, hi);
      }
    }
    if (lane == 0) {
      float* qo = (float*)(ws + QOFF);
      for (int i = 0; i < 6; ++i)
        for (int j = 0; j <= i; ++j) {
          float s = (i == j) ? 1e-7f : 0.0f;
          for (int k = 0; k <= j; ++k) s = fmaf(LQ[i * 6 + k], LQ[j * 6 + k], s);
          qo[TRI(i, j)] = s;
        }
      for (int i = 0; i < 3; ++i)
        for (int j = 0; j <= i; ++j) {
          float s = (i == j) ? 1e-7f : 0.0f;
          for (int k = 0; k <= j; ++k) s = fmaf(LR[i * 3 + k], LR[j * 3 + k], s);
          qo[21 + TRI(i, j)] = s;
        }
    }
  }

  int b = blockIdx.x * blockDim.x + threadIdx.x;
  if (b >= B) return;
  float Pf[36];
  const float4* p4 = (const float4*)(gP + (size_t)b * 36);
#pragma unroll
  for (int q = 0; q < 9; ++q) {
    float4 v = p4[q];
    Pf[q*4+0]=v.x; Pf[q*4+1]=v.y; Pf[q*4+2]=v.z; Pf[q*4+3]=v.w;
  }
  float base[21], Lt[21];
#pragma unroll
  for (int i = 0; i < 6; ++i)
#pragma unroll
    for (int j = 0; j <= i; ++j)
      base[TRI(i,j)] = 0.75f * (Pf[i*6+j] + Pf[j*6+i]) + ((i==j) ? 1e-5f : 0.0f);
#pragma unroll
  for (int k = 0; k < 6; ++k) {
    float s = base[TRI(k,k)];
#pragma unroll
    for (int m2 = 0; m2 < k; ++m2) s = fmaf(-Lt[TRI(k,m2)], Lt[TRI(k,m2)], s);
    float d = sqrtf(s);
    Lt[TRI(k,k)] = d;
    float inv = 1.0f / d;
#pragma unroll
    for (int i = k + 1; i < 6; ++i) {
      float s2 = base[TRI(i,k)];
#pragma unroll
      for (int m2 = 0; m2 < k; ++m2) s2 = fmaf(-Lt[TRI(i,m2)], Lt[TRI(k,m2)], s2);
      Lt[TRI(i,k)] = s2 * inv;
    }
  }
  float* lp = Lbuf + (size_t)b * 48;
#pragma unroll
  for (int c = 0; c < 6; ++c) {
#pragma unroll
    for (int f = 0; f < 6; ++f)
      lp[c * 8 + f] = (f >= c) ? Lt[TRI(f, c)] : 0.0f;
    lp[c * 8 + 6] = 0.0f; lp[c * 8 + 7] = 0.0f;
  }
}

// ---- main: one wave = 2 batches; zero-exchange K-loop; dup-row layer2 ----
__launch_bounds__(256, 8)
__global__ void ukf_main(const float* __restrict__ gx,
                         const float* __restrict__ gu,
                         const float* __restrict__ gb2,
                         const float* __restrict__ Lbuf,
                         const char*  __restrict__ ws,
                         float* __restrict__ Ubuf, int B) {
  __shared__ f32x4 ldsv[4][136];   // per wave: dx[32 cols][17] f32
  int lane = threadIdx.x & 63;
  int wid  = threadIdx.x >> 6;
  int p    = blockIdx.x * 4 + wid;
  if (2 * p >= B) return;
  int u   = lane >> 5;
  int c   = lane & 31;
  int q16 = lane >> 4, m16 = lane & 15;
  int bc  = 2 * p + ((lane >> 4) & 1);
  float* dxs = (float*)&ldsv[wid][0];

  // sigma column ids + vectorized L column load
  int   sidx = c & 15;
  float sgn = (sidx == 0 || sidx > 12) ? 0.0f : ((sidx <= 6) ? 1.0f : -1.0f);
  int   cc  = (sidx >= 1 && sidx <= 6) ? (sidx - 1) : ((sidx >= 7) ? (sidx - 7) : 0);
  if (cc > 5) cc = 5;
  const float* lpr = Lbuf + (size_t)bc * 48 + cc * 8;
  float4 La = *(const float4*)lpr;
  float2 Lb = *(const float2*)(lpr + 4);
  float Lc[6] = {La.x, La.y, La.z, La.w, Lb.x, Lb.y};

  float x0c[6];
  {
    const float* xb = gx + (size_t)bc * 6;
    float2 t0 = *(const float2*)(xb);
    float2 t1 = *(const float2*)(xb + 2);
    float2 t2 = *(const float2*)(xb + 4);
    x0c[0]=t0.x; x0c[1]=t0.y; x0c[2]=t1.x; x0c[3]=t1.y; x0c[4]=t2.x; x0c[5]=t2.y;
  }
  float2 uu = *(const float2*)(gu + (size_t)bc * 2);
  unsigned uu_pk = pk2(uu.x, uu.y);

  const char* wp = ws + lane * 96;
  bf16x8 A1v0 = *((const bf16x8*)wp);
  bf16x8 A1v1 = *((const bf16x8*)(wp + 16));
  bf16x8 A2v[4];
#pragma unroll
  for (int kq = 0; kq < 4; ++kq) A2v[kq] = *((const bf16x8*)(wp + 32 + kq * 16));
  float b2r[6];
#pragma unroll
  for (int i = 0; i < 6; ++i) b2r[i] = gb2[i];

  // xs (stage-0 input); fold b2 into bases
  float xs[6], sgnLp[6], xs005[6];
#pragma unroll
  for (int f = 0; f < 6; ++f) {
    float sl = sgn * Lc[f];
    xs[f] = x0c[f] + sl;
    sgnLp[f] = fmaf(0.01f, b2r[f], sl);           // dl base: sgnL + dt*b2
  }
  union { bf16x8 v; unsigned w[4]; } bx;
  bx.w[0] = u ? 0x00003F80u : pk2t(xs[0], xs[1]);
  bx.w[1] = pk2t(xs[2], xs[3]);
  bx.w[2] = pk2t(xs[4], xs[5]);
  bx.w[3] = uu_pk;
#pragma unroll
  for (int f = 0; f < 6; ++f) xs005[f] = fmaf(0.005f, b2r[f], xs[f]);

  f32x16 z16;
#pragma unroll
  for (int i = 0; i < 16; ++i) z16[i] = 0.0f;

  float ksum[6] = {0.f, 0.f, 0.f, 0.f, 0.f, 0.f};
#pragma unroll
  for (int st = 0; st < 4; ++st) {
    f32x16 d1a = __builtin_amdgcn_mfma_f32_32x32x16_bf16(A1v0, bx.v, z16, 0, 0, 0);
    f32x16 d1b = __builtin_amdgcn_mfma_f32_32x32x16_bf16(A1v1, bx.v, z16, 0, 0, 0);
    unsigned Hpk[16];
#pragma unroll
    for (int pr = 0; pr < 8; ++pr) Hpk[pr]     = tanh2_pk(d1a[2*pr], d1a[2*pr+1]);
#pragma unroll
    for (int pr = 0; pr < 8; ++pr) Hpk[8 + pr] = tanh2_pk(d1b[2*pr], d1b[2*pr+1]);
    // layer2: B-fragment = own Hpk[4kq..4kq+3]; A has duplicated feat rows
    f32x16 d2 = z16;
#pragma unroll
    for (int kq = 0; kq < 4; ++kq) {
      union { bf16x8 v; unsigned w[4]; } bh;
      bh.w[0] = Hpk[4*kq+0]; bh.w[1] = Hpk[4*kq+1];
      bh.w[2] = Hpk[4*kq+2]; bh.w[3] = Hpk[4*kq+3];
      d2 = __builtin_amdgcn_mfma_f32_32x32x16_bf16(A2v[kq], bh.v, d2, 0, 0, 0);
    }
    const float wks = (st == 0 || st == 3) ? 1.0f : 2.0f;
#pragma unroll
    for (int f = 0; f < 6; ++f) ksum[f] = fmaf(wks, d2[f], ksum[f]);
    if (st < 3) {
      const float cin = (st == 2) ? 0.01f : 0.005f;
      float xi[6];
#pragma unroll
      for (int f = 0; f < 6; ++f) {
        float basef = (st == 2) ? fmaf(0.005f, b2r[f], xs005[f]) : xs005[f];
        xi[f] = fmaf(cin, d2[f], basef);
      }
      bx.w[0] = u ? 0x00003F80u : pk2t(xi[0], xi[1]);
      bx.w[1] = pk2t(xi[2], xi[3]);
      bx.w[2] = pk2t(xi[4], xi[5]);
    }
  }

  // deltas -> LDS (stride 17, conflict-free); both halves identical, u==0 writes
  const float dt6 = 0.01f / 6.0f;
  if (u == 0) {
#pragma unroll
    for (int f = 0; f < 6; ++f) dxs[c * 17 + f] = fmaf(dt6, ksum[f], sgnLp[f]);
  }

  // ---- moments: two 16x16x32 MFMAs, shared B = dx ----
  float dxv[8];
#pragma unroll
  for (int j = 0; j < 8; ++j) dxv[j] = dxs[(8 * q16 + j) * 17 + m16];
  float wc0[8], wc1[8];
#pragma unroll
  for (int j = 0; j < 8; ++j) {
    float c0j = (j == 0) ? -0.25f : ONE3;
    float c1j = (j <= 4) ? ONE3 : 0.0f;
    wc0[j] = (q16 == 0) ? c0j : ((q16 == 1) ? c1j : 0.0f);
    wc1[j] = (q16 == 2) ? c0j : ((q16 == 3) ? c1j : 0.0f);
  }
  float wm00 = (q16 == 0) ? -3.0f : wc0[0];
  float wm10 = (q16 == 2) ? -3.0f : wc1[0];
  bool mlt6 = (m16 < 6), m6 = (m16 == 6), m7 = (m16 == 7);
  union { bf16x8 v; unsigned w[4]; } am0, am1, bw;
  {
    float a0[8], a1[8];
#pragma unroll
    for (int j = 0; j < 8; ++j) {
      float wmj0 = (j == 0) ? wm00 : wc0[j];
      float wmj1 = (j == 0) ? wm10 : wc1[j];
      float alt0 = m6 ? wc0[j] : (m7 ? wmj0 : 0.0f);
      float alt1 = m6 ? wc1[j] : (m7 ? wmj1 : 0.0f);
      a0[j] = mlt6 ? wc0[j] * dxv[j] : alt0;
      a1[j] = mlt6 ? wc1[j] * dxv[j] : alt1;
    }
#pragma unroll
    for (int pr = 0; pr < 4; ++pr) {
      am0.w[pr] = pk2(a0[2*pr], a0[2*pr+1]);
      am1.w[pr] = pk2(a1[2*pr], a1[2*pr+1]);
      bw.w[pr]  = pk2(dxv[2*pr], dxv[2*pr+1]);
    }
  }
  f32x4 zz = {0.0f, 0.0f, 0.0f, 0.0f};
  f32x4 Dm0 = __builtin_amdgcn_mfma_f32_16x16x32_bf16(am0.v, bw.v, zz, 0, 0, 0);
  f32x4 Dm1 = __builtin_amdgcn_mfma_f32_16x16x32_bf16(am1.v, bw.v, zz, 0, 0, 0);

  if (q16 < 2 && m16 < 6) {
    float* u0 = Ubuf + (size_t)(2 * p) * 48;
    float* u1 = Ubuf + (size_t)(2 * p + 1) * 48;
#pragma unroll
    for (int i = 0; i < 4; ++i) {
      u0[(4 * q16 + i) * 6 + m16] = Dm0[i];
      u1[(4 * q16 + i) * 6 + m16] = Dm1[i];
    }
  }
}

// ---- epilogue: 1 thread/batch ----
__global__ void ukf_epi(const float* __restrict__ gx,
                        const float* __restrict__ gy,
                        const char*  __restrict__ ws,
                        const float* __restrict__ Ubuf,
                        float* __restrict__ out, int B) {
  int b = blockIdx.x * blockDim.x + threadIdx.x;
  if (b >= B) return;
  const float* rec = Ubuf + (size_t)b * 48;
  float U[21], cbv[6], dbv[6];
#pragma unroll
  for (int i = 0; i < 6; ++i)
#pragma unroll
    for (int j = 0; j <= i; ++j) U[TRI(i,j)] = rec[i * 6 + j];
#pragma unroll
  for (int j = 0; j < 6; ++j) { cbv[j] = rec[36 + j]; dbv[j] = rec[42 + j]; }

  float x0[6];
  {
    const float* xb = gx + (size_t)b * 6;
    float2 t0 = *(const float2*)(xb);
    float2 t1 = *(const float2*)(xb + 2);
    float2 t2 = *(const float2*)(xb + 4);
    x0[0]=t0.x; x0[1]=t0.y; x0[2]=t1.x; x0[3]=t1.y; x0[4]=t2.x; x0[5]=t2.y;
  }
  const float* yb = gy + (size_t)b * 3;
  float yy0 = yb[0], yy1 = yb[1], yy2 = yb[2];

  const float* qro = (const float*)(ws + QOFF);
  float Qm[21], Rm[6];
#pragma unroll
  for (int t = 0; t < 21; ++t) Qm[t] = qro[t];
#pragma unroll
  for (int t = 0; t < 6; ++t) Rm[t] = qro[21 + t];

  float xp[6];
#pragma unroll
  for (int i = 0; i < 6; ++i) xp[i] = x0[i] + dbv[i];
  float D[21];
#pragma unroll
  for (int i = 0; i < 6; ++i)
#pragma unroll
    for (int j = 0; j <= i; ++j) {
      float v = U[TRI(i,j)];
      v -= cbv[i] * dbv[j];
      v -= dbv[i] * cbv[j];
      v = fmaf(3.75f * dbv[i], dbv[j], v);
      D[TRI(i,j)] = v;
    }
  float s00 = D[TRI(0,0)] + Rm[TRI(0,0)];
  float s10 = D[TRI(1,0)] + Rm[TRI(1,0)];
  float s11 = D[TRI(1,1)] + Rm[TRI(1,1)];
  float s20 = D[TRI(2,0)] + Rm[TRI(2,0)];
  float s21 = D[TRI(2,1)] + Rm[TRI(2,1)];
  float s22 = D[TRI(2,2)] + Rm[TRI(2,2)];
  float a00 = s00 + 1e-5f, a11 = s11 + 1e-5f, a22 = s22 + 1e-5f;
  float a10 = s10, a20 = s20, a21 = s21;
  float adj00 = a11*a22 - a21*a21;
  float adj01 = a20*a21 - a10*a22;
  float adj02 = a10*a21 - a11*a20;
  float adj11 = a00*a22 - a20*a20;
  float adj12 = a10*a20 - a00*a21;
  float adj22 = a00*a11 - a10*a10;
  float det  = a00*adj00 + a10*adj01 + a20*adj02;
  float idet = 1.0f / det;
  float I00 = adj00*idet, I01 = adj01*idet, I02 = adj02*idet;
  float I11 = adj11*idet, I12 = adj12*idet, I22 = adj22*idet;

#define DS(i,j) ((i) >= (j) ? D[TRI(i,j)] : D[TRI(j,i)])
  float K_[18];
#pragma unroll
  for (int i = 0; i < 6; ++i) {
    float c0 = DS(i,0), c1 = DS(i,1), c2 = DS(i,2);
    K_[i*3+0] = c0*I00 + c1*I01 + c2*I02;
    K_[i*3+1] = c0*I01 + c1*I11 + c2*I12;
    K_[i*3+2] = c0*I02 + c1*I12 + c2*I22;
  }
  float inn0 = yy0 - xp[0], inn1 = yy1 - xp[1], inn2 = yy2 - xp[2];
  float xu[6];
#pragma unroll
  for (int i = 0; i < 6; ++i)
    xu[i] = xp[i] + K_[i*3]*inn0 + K_[i*3+1]*inn1 + K_[i*3+2]*inn2;

  float KS[18];
#pragma unroll
  for (int i = 0; i < 6; ++i) {
    float k0 = K_[i*3], k1 = K_[i*3+1], k2 = K_[i*3+2];
    KS[i*3+0] = k0*s00 + k1*s10 + k2*s20;
    KS[i*3+1] = k0*s10 + k1*s11 + k2*s21;
    KS[i*3+2] = k0*s20 + k1*s21 + k2*s22;
  }
  float Pu[21];
#pragma unroll
  for (int i = 0; i < 6; ++i)
#pragma unroll
    for (int j = 0; j <= i; ++j) {
      float v = D[TRI(i,j)] + Qm[TRI(i,j)];
      v -= KS[i*3]*K_[j*3] + KS[i*3+1]*K_[j*3+1] + KS[i*3+2]*K_[j*3+2];
      Pu[TRI(i,j)] = v + ((i==j) ? 1e-4f : 0.0f);
    }

  float* o_xu = out;
  float* o_Pu = out + (size_t)6  * B;
  float* o_xp = out + (size_t)42 * B;
  float* o_Pp = out + (size_t)48 * B;
  float* o_yp = out + (size_t)84 * B;
  float* o_S  = out + (size_t)87 * B;
  float* o_K  = out + (size_t)96 * B;
  {
    float* pp = o_xu + (size_t)b * 6;
    ((float2*)pp)[0] = make_float2(xu[0], xu[1]);
    ((float2*)pp)[1] = make_float2(xu[2], xu[3]);
    ((float2*)pp)[2] = make_float2(xu[4], xu[5]);
  }
  {
    float* pp = o_Pu + (size_t)b * 36;
#pragma unroll
    for (int i = 0; i < 6; ++i)
#pragma unroll
      for (int j = 0; j < 6; j += 2) {
        float v0 = (i>=j)   ? Pu[TRI(i,j)]   : Pu[TRI(j,i)];
        float v1 = (i>=j+1) ? Pu[TRI(i,j+1)] : Pu[TRI(j+1,i)];
        *(float2*)(pp + i*6 + j) = make_float2(v0, v1);
      }
  }
  {
    float* pp = o_xp + (size_t)b * 6;
    ((float2*)pp)[0] = make_float2(xp[0], xp[1]);
    ((float2*)pp)[1] = make_float2(xp[2], xp[3]);
    ((float2*)pp)[2] = make_float2(xp[4], xp[5]);
  }
  {
    float* pp = o_Pp + (size_t)b * 36;
#pragma unroll
    for (int i = 0; i < 6; ++i)
#pragma unroll
      for (int j = 0; j < 6; j += 2) {
        float v0 = ((i>=j)   ? D[TRI(i,j)]   : D[TRI(j,i)])   + ((i>=j)   ? Qm[TRI(i,j)]   : Qm[TRI(j,i)]);
        float v1 = ((i>=j+1) ? D[TRI(i,j+1)] : D[TRI(j+1,i)]) + ((i>=j+1) ? Qm[TRI(i,j+1)] : Qm[TRI(j+1,i)]);
        *(float2*)(pp + i*6 + j) = make_float2(v0, v1);
      }
  }
  {
    float* pp = o_yp + (size_t)b * 3;
    pp[0] = xp[0]; pp[1] = xp[1]; pp[2] = xp[2];
  }
  {
    float* pp = o_S + (size_t)b * 9;
    pp[0]=s00; pp[1]=s10; pp[2]=s20;
    pp[3]=s10; pp[4]=s11; pp[5]=s21;
    pp[6]=s20; pp[7]=s21; pp[8]=s22;
  }
  {
    float* pp = o_K + (size_t)b * 18;
#pragma unroll
    for (int i = 0; i < 9; ++i)
      ((float2*)pp)[i] = make_float2(K_[i*2], K_[i*2+1]);
  }
}

extern "C" void kernel_launch(void* const* d_in, const int* in_sizes, int n_in,
                              void* d_out, int out_size, void* d_ws, size_t ws_size,
                              hipStream_t stream) {
  const float* x  = (const float*)d_in[0];
  const float* P  = (const float*)d_in[1];
  const float* u  = (const float*)d_in[2];
  const float* y  = (const float*)d_in[3];
  const float* LQ = (const float*)d_in[4];
  const float* LR = (const float*)d_in[5];
  const float* W1 = (const float*)d_in[6];
  const float* b1 = (const float*)d_in[7];
  const float* W2 = (const float*)d_in[8];
  const float* b2 = (const float*)d_in[9];
  float* out = (float*)d_out;
  char*  ws  = (char*)d_ws;
  int B = in_sizes[0] / 6;

  float* Lbuf = (float*)(ws + LOFF);
  float* Ubuf = (float*)(ws + LOFF + (size_t)B * 192);

  hipLaunchKernelGGL(prep_kernel, dim3((B + 255) / 256), dim3(256), 0, stream,
                     P, W1, b1, W2, LQ, LR, ws, Lbuf, B);
  hipLaunchKernelGGL(ukf_main, dim3((B + 7) / 8), dim3(256), 0, stream,
                     x, u, b2, (const float*)Lbuf, (const char*)ws, Ubuf, B);
  hipLaunchKernelGGL(ukf_epi, dim3((B + 255) / 256), dim3(256), 0, stream,
                     x, y, (const char*)ws, (const float*)Ubuf, out, B);
}

// Round 8
// 232.977 us; speedup vs baseline: 1.9078x; 1.9078x over previous
//
#include <hip/hip_runtime.h>
#include <math.h>

typedef __attribute__((ext_vector_type(8)))  short bf16x8;
typedef __attribute__((ext_vector_type(4)))  float f32x4;
typedef __attribute__((ext_vector_type(16))) float f32x16;
typedef __attribute__((ext_vector_type(2)))  float f32x2;

#define TRI(i,j) (((i)*((i)+1))/2 + (j))
#define ONE3 0.3333333333333333f
#define QOFF 6144   /* Q/R consts after 64*96B frag records */
#define LOFF 8192   /* cholesky L buffer: [batch][48] f32 (col c at c*8, 2 pad) */

// RNE f32->bf16 (moment fragments: precision matters)
static __device__ __forceinline__ unsigned short f2b(float f) {
  union { float f; unsigned u; } v; v.f = f;
  unsigned r = v.u + 0x7FFFu + ((v.u >> 16) & 1u);
  return (unsigned short)(r >> 16);
}
static __device__ __forceinline__ unsigned pk2(float lo, float hi) {
  return (unsigned)f2b(lo) | ((unsigned)f2b(hi) << 16);
}
// truncating pack (NN path, dt-damped)
static __device__ __forceinline__ unsigned pk2t(float lo, float hi) {
  return __builtin_amdgcn_perm(__float_as_uint(hi), __float_as_uint(lo), 0x07060302u);
}

// odd deg-7 tanh approx, fitted [-3,3]; no clamp (preactivations bounded, dt-damped)
#define TC0 0.970866f
#define TC1 (-0.217815f)
#define TC2 0.028904f
#define TC3 (-0.0014079f)

static __device__ __forceinline__ unsigned tanh2_pk(float a, float b) {
#if __has_builtin(__builtin_elementwise_fma)
  f32x2 z; z[0] = a; z[1] = b;
  f32x2 k3 = {TC3, TC3}, k2 = {TC2, TC2}, k1 = {TC1, TC1}, k0 = {TC0, TC0};
  f32x2 t = z * z;
  f32x2 p = __builtin_elementwise_fma(t, k3, k2);
  p = __builtin_elementwise_fma(p, t, k1);
  p = __builtin_elementwise_fma(p, t, k0);
  f32x2 r = z * p;
  return pk2t(r[0], r[1]);
#else
  float ta = a * a, tb = b * b;
  float pa = fmaf(fmaf(fmaf(TC3, ta, TC2), ta, TC1), ta, TC0);
  float pb = fmaf(fmaf(fmaf(TC3, tb, TC2), tb, TC1), tb, TC0);
  return pk2t(a * pa, b * pb);
#endif
}

// ---- prep: per-batch cholesky -> Lbuf; block 0 lanes 0..63 also pack weight frags ----
// A2 k-slot perm: hidden(kq,u,j) = 32*(kq>>1) + 16*(kq&1) + 4u + (j<4?j:j+4) so each
// lane's D1 C-layout regs Hpk[4kq..4kq+3] ARE the layer-2 B fragment (no exchange).
// A2 m-rows DUPLICATED so both u-halves own all 6 feats in d2 regs 0..5:
//   rows 0-3 = feats0-3, rows 4-7 = feats0-3, rows 8-9 = feats4-5, rows 12-13 = feats4-5.
__global__ void prep_kernel(const float* __restrict__ gP,
                            const float* __restrict__ W1, const float* __restrict__ b1,
                            const float* __restrict__ W2,
                            const float* __restrict__ LQ, const float* __restrict__ LR,
                            char* __restrict__ ws, float* __restrict__ Lbuf, int B) {
  if (blockIdx.x == 0 && threadIdx.x < 64) {
    int lane = threadIdx.x;
    int mr = lane & 31, u = lane >> 5;
    unsigned* A1 = (unsigned*)(ws + lane * 96);
    unsigned* A2 = (unsigned*)(ws + lane * 96 + 32);
#pragma unroll
    for (int t = 0; t < 2; ++t) {
      int h = 32 * t + mr;
      if (u == 0) {
#pragma unroll
        for (int p = 0; p < 4; ++p)
          A1[t * 4 + p] = pk2(W1[(2 * p) * 64 + h], W1[(2 * p + 1) * 64 + h]);
      } else {
        A1[t * 4 + 0] = pk2(b1[h], 0.0f);
        A1[t * 4 + 1] = 0u; A1[t * 4 + 2] = 0u; A1[t * 4 + 3] = 0u;
      }
    }
    int fr = (mr < 4) ? mr
           : (mr < 10) ? (mr - 4)
           : (mr >= 12 && mr < 14) ? (mr - 8) : -1;
#pragma unroll
    for (int kq = 0; kq < 4; ++kq) {
#pragma unroll
      for (int p = 0; p < 4; ++p) {
        int rm = 2 * p + ((p >= 2) ? 4 : 0);
        int hid = 32 * (kq >> 1) + 16 * (kq & 1) + 4 * u + rm;
        float lo = (fr >= 0) ? W2[hid * 6 + fr] : 0.0f;
        float hi = (fr >= 0) ? W2[(hid + 1) * 6 + fr] : 0.0f;
        A2[kq * 4 + p] = pk2(lo, hi);
      }
    }
    if (lane == 0) {
      float* qo = (float*)(ws + QOFF);
      for (int i = 0; i < 6; ++i)
        for (int j = 0; j <= i; ++j) {
          float s = (i == j) ? 1e-7f : 0.0f;
          for (int k = 0; k <= j; ++k) s = fmaf(LQ[i * 6 + k], LQ[j * 6 + k], s);
          qo[TRI(i, j)] = s;
        }
      for (int i = 0; i < 3; ++i)
        for (int j = 0; j <= i; ++j) {
          float s = (i == j) ? 1e-7f : 0.0f;
          for (int k = 0; k <= j; ++k) s = fmaf(LR[i * 3 + k], LR[j * 3 + k], s);
          qo[21 + TRI(i, j)] = s;
        }
    }
  }

  int b = blockIdx.x * blockDim.x + threadIdx.x;
  if (b >= B) return;
  float Pf[36];
  const float4* p4 = (const float4*)(gP + (size_t)b * 36);
#pragma unroll
  for (int q = 0; q < 9; ++q) {
    float4 v = p4[q];
    Pf[q*4+0]=v.x; Pf[q*4+1]=v.y; Pf[q*4+2]=v.z; Pf[q*4+3]=v.w;
  }
  float base[21], Lt[21];
#pragma unroll
  for (int i = 0; i < 6; ++i)
#pragma unroll
    for (int j = 0; j <= i; ++j)
      base[TRI(i,j)] = 0.75f * (Pf[i*6+j] + Pf[j*6+i]) + ((i==j) ? 1e-5f : 0.0f);
#pragma unroll
  for (int k = 0; k < 6; ++k) {
    float s = base[TRI(k,k)];
#pragma unroll
    for (int m2 = 0; m2 < k; ++m2) s = fmaf(-Lt[TRI(k,m2)], Lt[TRI(k,m2)], s);
    float d = sqrtf(s);
    Lt[TRI(k,k)] = d;
    float inv = 1.0f / d;
#pragma unroll
    for (int i = k + 1; i < 6; ++i) {
      float s2 = base[TRI(i,k)];
#pragma unroll
      for (int m2 = 0; m2 < k; ++m2) s2 = fmaf(-Lt[TRI(i,m2)], Lt[TRI(k,m2)], s2);
      Lt[TRI(i,k)] = s2 * inv;
    }
  }
  float* lp = Lbuf + (size_t)b * 48;
#pragma unroll
  for (int c = 0; c < 6; ++c) {
#pragma unroll
    for (int f = 0; f < 6; ++f)
      lp[c * 8 + f] = (f >= c) ? Lt[TRI(f, c)] : 0.0f;
    lp[c * 8 + 6] = 0.0f; lp[c * 8 + 7] = 0.0f;
  }
}

// ---- main: one wave = 2 batches; zero-exchange K-loop; dup-row layer2 ----
// NOTE: __launch_bounds__(256,4) — (256,8) caps VGPR at 64 and spills the K-loop
// to scratch (R7: 1.35 GB HBM traffic, 3x slowdown). 48-56 VGPR live state needs
// the 128-VGPR budget that min-waves=4 provides.
__launch_bounds__(256, 4)
__global__ void ukf_main(const float* __restrict__ gx,
                         const float* __restrict__ gu,
                         const float* __restrict__ gb2,
                         const float* __restrict__ Lbuf,
                         const char*  __restrict__ ws,
                         float* __restrict__ Ubuf, int B) {
  __shared__ f32x4 ldsv[4][136];   // per wave: dx[32 cols][17] f32
  int lane = threadIdx.x & 63;
  int wid  = threadIdx.x >> 6;
  int p    = blockIdx.x * 4 + wid;
  if (2 * p >= B) return;
  int u   = lane >> 5;
  int c   = lane & 31;
  int q16 = lane >> 4, m16 = lane & 15;
  int bc  = 2 * p + ((lane >> 4) & 1);
  float* dxs = (float*)&ldsv[wid][0];

  // sigma column ids + vectorized L column load
  int   sidx = c & 15;
  float sgn = (sidx == 0 || sidx > 12) ? 0.0f : ((sidx <= 6) ? 1.0f : -1.0f);
  int   cc  = (sidx >= 1 && sidx <= 6) ? (sidx - 1) : ((sidx >= 7) ? (sidx - 7) : 0);
  if (cc > 5) cc = 5;
  const float* lpr = Lbuf + (size_t)bc * 48 + cc * 8;
  float4 La = *(const float4*)lpr;
  float2 Lb = *(const float2*)(lpr + 4);
  float Lc[6] = {La.x, La.y, La.z, La.w, Lb.x, Lb.y};

  float x0c[6];
  {
    const float* xb = gx + (size_t)bc * 6;
    float2 t0 = *(const float2*)(xb);
    float2 t1 = *(const float2*)(xb + 2);
    float2 t2 = *(const float2*)(xb + 4);
    x0c[0]=t0.x; x0c[1]=t0.y; x0c[2]=t1.x; x0c[3]=t1.y; x0c[4]=t2.x; x0c[5]=t2.y;
  }
  float2 uu = *(const float2*)(gu + (size_t)bc * 2);
  unsigned uu_pk = pk2(uu.x, uu.y);

  const char* wp = ws + lane * 96;
  bf16x8 A1v0 = *((const bf16x8*)wp);
  bf16x8 A1v1 = *((const bf16x8*)(wp + 16));
  bf16x8 A2v[4];
#pragma unroll
  for (int kq = 0; kq < 4; ++kq) A2v[kq] = *((const bf16x8*)(wp + 32 + kq * 16));
  float b2r[6];
#pragma unroll
  for (int i = 0; i < 6; ++i) b2r[i] = gb2[i];

  // xs (stage-0 input); fold b2 into bases
  float xs[6], sgnLp[6], xs005[6];
#pragma unroll
  for (int f = 0; f < 6; ++f) {
    float sl = sgn * Lc[f];
    xs[f] = x0c[f] + sl;
    sgnLp[f] = fmaf(0.01f, b2r[f], sl);           // dl base: sgnL + dt*b2
  }
  union { bf16x8 v; unsigned w[4]; } bx;
  bx.w[0] = u ? 0x00003F80u : pk2t(xs[0], xs[1]);
  bx.w[1] = pk2t(xs[2], xs[3]);
  bx.w[2] = pk2t(xs[4], xs[5]);
  bx.w[3] = uu_pk;
#pragma unroll
  for (int f = 0; f < 6; ++f) xs005[f] = fmaf(0.005f, b2r[f], xs[f]);

  f32x16 z16;
#pragma unroll
  for (int i = 0; i < 16; ++i) z16[i] = 0.0f;

  float ksum[6] = {0.f, 0.f, 0.f, 0.f, 0.f, 0.f};
#pragma unroll
  for (int st = 0; st < 4; ++st) {
    f32x16 d1a = __builtin_amdgcn_mfma_f32_32x32x16_bf16(A1v0, bx.v, z16, 0, 0, 0);
    f32x16 d1b = __builtin_amdgcn_mfma_f32_32x32x16_bf16(A1v1, bx.v, z16, 0, 0, 0);
    unsigned Hpk[16];
#pragma unroll
    for (int pr = 0; pr < 8; ++pr) Hpk[pr]     = tanh2_pk(d1a[2*pr], d1a[2*pr+1]);
#pragma unroll
    for (int pr = 0; pr < 8; ++pr) Hpk[8 + pr] = tanh2_pk(d1b[2*pr], d1b[2*pr+1]);
    // layer2: B-fragment = own Hpk[4kq..4kq+3]; A has duplicated feat rows
    f32x16 d2 = z16;
#pragma unroll
    for (int kq = 0; kq < 4; ++kq) {
      union { bf16x8 v; unsigned w[4]; } bh;
      bh.w[0] = Hpk[4*kq+0]; bh.w[1] = Hpk[4*kq+1];
      bh.w[2] = Hpk[4*kq+2]; bh.w[3] = Hpk[4*kq+3];
      d2 = __builtin_amdgcn_mfma_f32_32x32x16_bf16(A2v[kq], bh.v, d2, 0, 0, 0);
    }
    const float wks = (st == 0 || st == 3) ? 1.0f : 2.0f;
#pragma unroll
    for (int f = 0; f < 6; ++f) ksum[f] = fmaf(wks, d2[f], ksum[f]);
    if (st < 3) {
      const float cin = (st == 2) ? 0.01f : 0.005f;
      float xi[6];
#pragma unroll
      for (int f = 0; f < 6; ++f) {
        float basef = (st == 2) ? fmaf(0.005f, b2r[f], xs005[f]) : xs005[f];
        xi[f] = fmaf(cin, d2[f], basef);
      }
      bx.w[0] = u ? 0x00003F80u : pk2t(xi[0], xi[1]);
      bx.w[1] = pk2t(xi[2], xi[3]);
      bx.w[2] = pk2t(xi[4], xi[5]);
    }
  }

  // deltas -> LDS (stride 17, conflict-free); both halves identical, u==0 writes
  const float dt6 = 0.01f / 6.0f;
  if (u == 0) {
#pragma unroll
    for (int f = 0; f < 6; ++f) dxs[c * 17 + f] = fmaf(dt6, ksum[f], sgnLp[f]);
  }

  // ---- moments: two 16x16x32 MFMAs, shared B = dx ----
  float dxv[8];
#pragma unroll
  for (int j = 0; j < 8; ++j) dxv[j] = dxs[(8 * q16 + j) * 17 + m16];
  float wc0[8], wc1[8];
#pragma unroll
  for (int j = 0; j < 8; ++j) {
    float c0j = (j == 0) ? -0.25f : ONE3;
    float c1j = (j <= 4) ? ONE3 : 0.0f;
    wc0[j] = (q16 == 0) ? c0j : ((q16 == 1) ? c1j : 0.0f);
    wc1[j] = (q16 == 2) ? c0j : ((q16 == 3) ? c1j : 0.0f);
  }
  float wm00 = (q16 == 0) ? -3.0f : wc0[0];
  float wm10 = (q16 == 2) ? -3.0f : wc1[0];
  bool mlt6 = (m16 < 6), m6 = (m16 == 6), m7 = (m16 == 7);
  union { bf16x8 v; unsigned w[4]; } am0, am1, bw;
  {
    float a0[8], a1[8];
#pragma unroll
    for (int j = 0; j < 8; ++j) {
      float wmj0 = (j == 0) ? wm00 : wc0[j];
      float wmj1 = (j == 0) ? wm10 : wc1[j];
      float alt0 = m6 ? wc0[j] : (m7 ? wmj0 : 0.0f);
      float alt1 = m6 ? wc1[j] : (m7 ? wmj1 : 0.0f);
      a0[j] = mlt6 ? wc0[j] * dxv[j] : alt0;
      a1[j] = mlt6 ? wc1[j] * dxv[j] : alt1;
    }
#pragma unroll
    for (int pr = 0; pr < 4; ++pr) {
      am0.w[pr] = pk2(a0[2*pr], a0[2*pr+1]);
      am1.w[pr] = pk2(a1[2*pr], a1[2*pr+1]);
      bw.w[pr]  = pk2(dxv[2*pr], dxv[2*pr+1]);
    }
  }
  f32x4 zz = {0.0f, 0.0f, 0.0f, 0.0f};
  f32x4 Dm0 = __builtin_amdgcn_mfma_f32_16x16x32_bf16(am0.v, bw.v, zz, 0, 0, 0);
  f32x4 Dm1 = __builtin_amdgcn_mfma_f32_16x16x32_bf16(am1.v, bw.v, zz, 0, 0, 0);

  if (q16 < 2 && m16 < 6) {
    float* u0 = Ubuf + (size_t)(2 * p) * 48;
    float* u1 = Ubuf + (size_t)(2 * p + 1) * 48;
#pragma unroll
    for (int i = 0; i < 4; ++i) {
      u0[(4 * q16 + i) * 6 + m16] = Dm0[i];
      u1[(4 * q16 + i) * 6 + m16] = Dm1[i];
    }
  }
}

// ---- epilogue: 1 thread/batch ----
__global__ void ukf_epi(const float* __restrict__ gx,
                        const float* __restrict__ gy,
                        const char*  __restrict__ ws,
                        const float* __restrict__ Ubuf,
                        float* __restrict__ out, int B) {
  int b = blockIdx.x * blockDim.x + threadIdx.x;
  if (b >= B) return;
  const float* rec = Ubuf + (size_t)b * 48;
  float U[21], cbv[6], dbv[6];
#pragma unroll
  for (int i = 0; i < 6; ++i)
#pragma unroll
    for (int j = 0; j <= i; ++j) U[TRI(i,j)] = rec[i * 6 + j];
#pragma unroll
  for (int j = 0; j < 6; ++j) { cbv[j] = rec[36 + j]; dbv[j] = rec[42 + j]; }

  float x0[6];
  {
    const float* xb = gx + (size_t)b * 6;
    float2 t0 = *(const float2*)(xb);
    float2 t1 = *(const float2*)(xb + 2);
    float2 t2 = *(const float2*)(xb + 4);
    x0[0]=t0.x; x0[1]=t0.y; x0[2]=t1.x; x0[3]=t1.y; x0[4]=t2.x; x0[5]=t2.y;
  }
  const float* yb = gy + (size_t)b * 3;
  float yy0 = yb[0], yy1 = yb[1], yy2 = yb[2];

  const float* qro = (const float*)(ws + QOFF);
  float Qm[21], Rm[6];
#pragma unroll
  for (int t = 0; t < 21; ++t) Qm[t] = qro[t];
#pragma unroll
  for (int t = 0; t < 6; ++t) Rm[t] = qro[21 + t];

  float xp[6];
#pragma unroll
  for (int i = 0; i < 6; ++i) xp[i] = x0[i] + dbv[i];
  float D[21];
#pragma unroll
  for (int i = 0; i < 6; ++i)
#pragma unroll
    for (int j = 0; j <= i; ++j) {
      float v = U[TRI(i,j)];
      v -= cbv[i] * dbv[j];
      v -= dbv[i] * cbv[j];
      v = fmaf(3.75f * dbv[i], dbv[j], v);
      D[TRI(i,j)] = v;
    }
  float s00 = D[TRI(0,0)] + Rm[TRI(0,0)];
  float s10 = D[TRI(1,0)] + Rm[TRI(1,0)];
  float s11 = D[TRI(1,1)] + Rm[TRI(1,1)];
  float s20 = D[TRI(2,0)] + Rm[TRI(2,0)];
  float s21 = D[TRI(2,1)] + Rm[TRI(2,1)];
  float s22 = D[TRI(2,2)] + Rm[TRI(2,2)];
  float a00 = s00 + 1e-5f, a11 = s11 + 1e-5f, a22 = s22 + 1e-5f;
  float a10 = s10, a20 = s20, a21 = s21;
  float adj00 = a11*a22 - a21*a21;
  float adj01 = a20*a21 - a10*a22;
  float adj02 = a10*a21 - a11*a20;
  float adj11 = a00*a22 - a20*a20;
  float adj12 = a10*a20 - a00*a21;
  float adj22 = a00*a11 - a10*a10;
  float det  = a00*adj00 + a10*adj01 + a20*adj02;
  float idet = 1.0f / det;
  float I00 = adj00*idet, I01 = adj01*idet, I02 = adj02*idet;
  float I11 = adj11*idet, I12 = adj12*idet, I22 = adj22*idet;

#define DS(i,j) ((i) >= (j) ? D[TRI(i,j)] : D[TRI(j,i)])
  float K_[18];
#pragma unroll
  for (int i = 0; i < 6; ++i) {
    float c0 = DS(i,0), c1 = DS(i,1), c2 = DS(i,2);
    K_[i*3+0] = c0*I00 + c1*I01 + c2*I02;
    K_[i*3+1] = c0*I01 + c1*I11 + c2*I12;
    K_[i*3+2] = c0*I02 + c1*I12 + c2*I22;
  }
  float inn0 = yy0 - xp[0], inn1 = yy1 - xp[1], inn2 = yy2 - xp[2];
  float xu[6];
#pragma unroll
  for (int i = 0; i < 6; ++i)
    xu[i] = xp[i] + K_[i*3]*inn0 + K_[i*3+1]*inn1 + K_[i*3+2]*inn2;

  float KS[18];
#pragma unroll
  for (int i = 0; i < 6; ++i) {
    float k0 = K_[i*3], k1 = K_[i*3+1], k2 = K_[i*3+2];
    KS[i*3+0] = k0*s00 + k1*s10 + k2*s20;
    KS[i*3+1] = k0*s10 + k1*s11 + k2*s21;
    KS[i*3+2] = k0*s20 + k1*s21 + k2*s22;
  }
  float Pu[21];
#pragma unroll
  for (int i = 0; i < 6; ++i)
#pragma unroll
    for (int j = 0; j <= i; ++j) {
      float v = D[TRI(i,j)] + Qm[TRI(i,j)];
      v -= KS[i*3]*K_[j*3] + KS[i*3+1]*K_[j*3+1] + KS[i*3+2]*K_[j*3+2];
      Pu[TRI(i,j)] = v + ((i==j) ? 1e-4f : 0.0f);
    }

  float* o_xu = out;
  float* o_Pu = out + (size_t)6  * B;
  float* o_xp = out + (size_t)42 * B;
  float* o_Pp = out + (size_t)48 * B;
  float* o_yp = out + (size_t)84 * B;
  float* o_S  = out + (size_t)87 * B;
  float* o_K  = out + (size_t)96 * B;
  {
    float* pp = o_xu + (size_t)b * 6;
    ((float2*)pp)[0] = make_float2(xu[0], xu[1]);
    ((float2*)pp)[1] = make_float2(xu[2], xu[3]);
    ((float2*)pp)[2] = make_float2(xu[4], xu[5]);
  }
  {
    float* pp = o_Pu + (size_t)b * 36;
#pragma unroll
    for (int i = 0; i < 6; ++i)
#pragma unroll
      for (int j = 0; j < 6; j += 2) {
        float v0 = (i>=j)   ? Pu[TRI(i,j)]   : Pu[TRI(j,i)];
        float v1 = (i>=j+1) ? Pu[TRI(i,j+1)] : Pu[TRI(j+1,i)];
        *(float2*)(pp + i*6 + j) = make_float2(v0, v1);
      }
  }
  {
    float* pp = o_xp + (size_t)b * 6;
    ((float2*)pp)[0] = make_float2(xp[0], xp[1]);
    ((float2*)pp)[1] = make_float2(xp[2], xp[3]);
    ((float2*)pp)[2] = make_float2(xp[4], xp[5]);
  }
  {
    float* pp = o_Pp + (size_t)b * 36;
#pragma unroll
    for (int i = 0; i < 6; ++i)
#pragma unroll
      for (int j = 0; j < 6; j += 2) {
        float v0 = ((i>=j)   ? D[TRI(i,j)]   : D[TRI(j,i)])   + ((i>=j)   ? Qm[TRI(i,j)]   : Qm[TRI(j,i)]);
        float v1 = ((i>=j+1) ? D[TRI(i,j+1)] : D[TRI(j+1,i)]) + ((i>=j+1) ? Qm[TRI(i,j+1)] : Qm[TRI(j+1,i)]);
        *(float2*)(pp + i*6 + j) = make_float2(v0, v1);
      }
  }
  {
    float* pp = o_yp + (size_t)b * 3;
    pp[0] = xp[0]; pp[1] = xp[1]; pp[2] = xp[2];
  }
  {
    float* pp = o_S + (size_t)b * 9;
    pp[0]=s00; pp[1]=s10; pp[2]=s20;
    pp[3]=s10; pp[4]=s11; pp[5]=s21;
    pp[6]=s20; pp[7]=s21; pp[8]=s22;
  }
  {
    float* pp = o_K + (size_t)b * 18;
#pragma unroll
    for (int i = 0; i < 9; ++i)
      ((float2*)pp)[i] = make_float2(K_[i*2], K_[i*2+1]);
  }
}

extern "C" void kernel_launch(void* const* d_in, const int* in_sizes, int n_in,
                              void* d_out, int out_size, void* d_ws, size_t ws_size,
                              hipStream_t stream) {
  const float* x  = (const float*)d_in[0];
  const float* P  = (const float*)d_in[1];
  const float* u  = (const float*)d_in[2];
  const float* y  = (const float*)d_in[3];
  const float* LQ = (const float*)d_in[4];
  const float* LR = (const float*)d_in[5];
  const float* W1 = (const float*)d_in[6];
  const float* b1 = (const float*)d_in[7];
  const float* W2 = (const float*)d_in[8];
  const float* b2 = (const float*)d_in[9];
  float* out = (float*)d_out;
  char*  ws  = (char*)d_ws;
  int B = in_sizes[0] / 6;

  float* Lbuf = (float*)(ws + LOFF);
  float* Ubuf = (float*)(ws + LOFF + (size_t)B * 192);

  hipLaunchKernelGGL(prep_kernel, dim3((B + 255) / 256), dim3(256), 0, stream,
                     P, W1, b1, W2, LQ, LR, ws, Lbuf, B);
  hipLaunchKernelGGL(ukf_main, dim3((B + 7) / 8), dim3(256), 0, stream,
                     x, u, b2, (const float*)Lbuf, (const char*)ws, Ubuf, B);
  hipLaunchKernelGGL(ukf_epi, dim3((B + 255) / 256), dim3(256), 0, stream,
                     x, y, (const char*)ws, (const float*)Ubuf, out, B);
}

// Round 9
// 227.824 us; speedup vs baseline: 1.9509x; 1.0226x over previous
//
#include <hip/hip_runtime.h>
#include <math.h>

typedef __attribute__((ext_vector_type(8)))  short bf16x8;
typedef __attribute__((ext_vector_type(4)))  float f32x4;
typedef __attribute__((ext_vector_type(16))) float f32x16;
typedef __attribute__((ext_vector_type(2)))  float f32x2;

#define TRI(i,j) (((i)*((i)+1))/2 + (j))
#define ONE3 0.3333333333333333f
#define QOFF 6144   /* Q/R consts after 64*96B frag records */
#define LOFF 8192   /* cholesky L buffer: [batch][48] f32 (col c at c*8, 2 pad) */

// RNE f32->bf16 (moment fragments: precision matters)
static __device__ __forceinline__ unsigned short f2b(float f) {
  union { float f; unsigned u; } v; v.f = f;
  unsigned r = v.u + 0x7FFFu + ((v.u >> 16) & 1u);
  return (unsigned short)(r >> 16);
}
static __device__ __forceinline__ unsigned pk2(float lo, float hi) {
  return (unsigned)f2b(lo) | ((unsigned)f2b(hi) << 16);
}
// truncating pack (NN path, dt-damped)
static __device__ __forceinline__ unsigned pk2t(float lo, float hi) {
  return __builtin_amdgcn_perm(__float_as_uint(hi), __float_as_uint(lo), 0x07060302u);
}

// odd deg-7 tanh approx, fitted [-3,3]; no clamp (preactivations bounded, dt-damped)
#define TC0 0.970866f
#define TC1 (-0.217815f)
#define TC2 0.028904f
#define TC3 (-0.0014079f)

static __device__ __forceinline__ unsigned tanh2_pk(float a, float b) {
#if __has_builtin(__builtin_elementwise_fma)
  f32x2 z; z[0] = a; z[1] = b;
  f32x2 k3 = {TC3, TC3}, k2 = {TC2, TC2}, k1 = {TC1, TC1}, k0 = {TC0, TC0};
  f32x2 t = z * z;
  f32x2 p = __builtin_elementwise_fma(t, k3, k2);
  p = __builtin_elementwise_fma(p, t, k1);
  p = __builtin_elementwise_fma(p, t, k0);
  f32x2 r = z * p;
  return pk2t(r[0], r[1]);
#else
  float ta = a * a, tb = b * b;
  float pa = fmaf(fmaf(fmaf(TC3, ta, TC2), ta, TC1), ta, TC0);
  float pb = fmaf(fmaf(fmaf(TC3, tb, TC2), tb, TC1), tb, TC0);
  return pk2t(a * pa, b * pb);
#endif
}

// ---- prep: per-batch cholesky -> Lbuf (float4 stores); block 0 packs weight frags ----
// A2 k-slot perm: hidden(kq,u,j) = 32*(kq>>1) + 16*(kq&1) + 4u + (j<4?j:j+4) so each
// lane's D1 C-layout regs Hpk[4kq..4kq+3] ARE the layer-2 B fragment (no exchange).
// A2 m-rows DUPLICATED so both u-halves own all 6 feats in d2 regs 0..5.
__global__ void prep_kernel(const float* __restrict__ gP,
                            const float* __restrict__ W1, const float* __restrict__ b1,
                            const float* __restrict__ W2,
                            const float* __restrict__ LQ, const float* __restrict__ LR,
                            char* __restrict__ ws, float* __restrict__ Lbuf, int B) {
  if (blockIdx.x == 0 && threadIdx.x < 64) {
    int lane = threadIdx.x;
    int mr = lane & 31, u = lane >> 5;
    unsigned* A1 = (unsigned*)(ws + lane * 96);
    unsigned* A2 = (unsigned*)(ws + lane * 96 + 32);
#pragma unroll
    for (int t = 0; t < 2; ++t) {
      int h = 32 * t + mr;
      if (u == 0) {
#pragma unroll
        for (int p = 0; p < 4; ++p)
          A1[t * 4 + p] = pk2(W1[(2 * p) * 64 + h], W1[(2 * p + 1) * 64 + h]);
      } else {
        A1[t * 4 + 0] = pk2(b1[h], 0.0f);
        A1[t * 4 + 1] = 0u; A1[t * 4 + 2] = 0u; A1[t * 4 + 3] = 0u;
      }
    }
    int fr = (mr < 4) ? mr
           : (mr < 10) ? (mr - 4)
           : (mr >= 12 && mr < 14) ? (mr - 8) : -1;
#pragma unroll
    for (int kq = 0; kq < 4; ++kq) {
#pragma unroll
      for (int p = 0; p < 4; ++p) {
        int rm = 2 * p + ((p >= 2) ? 4 : 0);
        int hid = 32 * (kq >> 1) + 16 * (kq & 1) + 4 * u + rm;
        float lo = (fr >= 0) ? W2[hid * 6 + fr] : 0.0f;
        float hi = (fr >= 0) ? W2[(hid + 1) * 6 + fr] : 0.0f;
        A2[kq * 4 + p] = pk2(lo, hi);
      }
    }
    if (lane == 0) {
      float* qo = (float*)(ws + QOFF);
      for (int i = 0; i < 6; ++i)
        for (int j = 0; j <= i; ++j) {
          float s = (i == j) ? 1e-7f : 0.0f;
          for (int k = 0; k <= j; ++k) s = fmaf(LQ[i * 6 + k], LQ[j * 6 + k], s);
          qo[TRI(i, j)] = s;
        }
      for (int i = 0; i < 3; ++i)
        for (int j = 0; j <= i; ++j) {
          float s = (i == j) ? 1e-7f : 0.0f;
          for (int k = 0; k <= j; ++k) s = fmaf(LR[i * 3 + k], LR[j * 3 + k], s);
          qo[21 + TRI(i, j)] = s;
        }
    }
  }

  int b = blockIdx.x * blockDim.x + threadIdx.x;
  if (b >= B) return;
  float Pf[36];
  const float4* p4 = (const float4*)(gP + (size_t)b * 36);
#pragma unroll
  for (int q = 0; q < 9; ++q) {
    float4 v = p4[q];
    Pf[q*4+0]=v.x; Pf[q*4+1]=v.y; Pf[q*4+2]=v.z; Pf[q*4+3]=v.w;
  }
  float base[21], Lt[21];
#pragma unroll
  for (int i = 0; i < 6; ++i)
#pragma unroll
    for (int j = 0; j <= i; ++j)
      base[TRI(i,j)] = 0.75f * (Pf[i*6+j] + Pf[j*6+i]) + ((i==j) ? 1e-5f : 0.0f);
#pragma unroll
  for (int k = 0; k < 6; ++k) {
    float s = base[TRI(k,k)];
#pragma unroll
    for (int m2 = 0; m2 < k; ++m2) s = fmaf(-Lt[TRI(k,m2)], Lt[TRI(k,m2)], s);
    float rs = __builtin_amdgcn_rsqf(s);     // s >= 1e-5 (SPD + jitter)
    float d  = s * rs;                        // sqrt(s)
    Lt[TRI(k,k)] = d;
    float inv = rs;                           // 1/sqrt(s) == 1/d
#pragma unroll
    for (int i = k + 1; i < 6; ++i) {
      float s2 = base[TRI(i,k)];
#pragma unroll
      for (int m2 = 0; m2 < k; ++m2) s2 = fmaf(-Lt[TRI(i,m2)], Lt[TRI(k,m2)], s2);
      Lt[TRI(i,k)] = s2 * inv;
    }
  }
  float4* lp4 = (float4*)(Lbuf + (size_t)b * 48);   // 192 B, 16 B aligned
#pragma unroll
  for (int c = 0; c < 6; ++c) {
    float v[6];
#pragma unroll
    for (int f = 0; f < 6; ++f) v[f] = (f >= c) ? Lt[TRI(f, c)] : 0.0f;
    lp4[c * 2 + 0] = make_float4(v[0], v[1], v[2], v[3]);
    lp4[c * 2 + 1] = make_float4(v[4], v[5], 0.0f, 0.0f);
  }
}

// ---- main: one wave = 2 batches; zero-exchange K-loop; dup-row layer2 ----
// NOTE: __launch_bounds__(256,4) — (256,8) caps VGPR at 64 and spills the K-loop
// to scratch (R7: 1.35 GB HBM traffic, 3x slowdown).
__launch_bounds__(256, 4)
__global__ void ukf_main(const float* __restrict__ gx,
                         const float* __restrict__ gu,
                         const float* __restrict__ gb2,
                         const float* __restrict__ Lbuf,
                         const char*  __restrict__ ws,
                         float* __restrict__ Ubuf, int B) {
  __shared__ f32x4 ldsv[4][136];   // per wave: dx[32 cols][17] f32
  int lane = threadIdx.x & 63;
  int wid  = threadIdx.x >> 6;
  int p    = blockIdx.x * 4 + wid;
  if (2 * p >= B) return;
  int u   = lane >> 5;
  int c   = lane & 31;
  int q16 = lane >> 4, m16 = lane & 15;
  int bc  = 2 * p + ((lane >> 4) & 1);
  float* dxs = (float*)&ldsv[wid][0];

  // sigma column ids + vectorized L column load
  int   sidx = c & 15;
  float sgn = (sidx == 0 || sidx > 12) ? 0.0f : ((sidx <= 6) ? 1.0f : -1.0f);
  int   cc  = (sidx >= 1 && sidx <= 6) ? (sidx - 1) : ((sidx >= 7) ? (sidx - 7) : 0);
  if (cc > 5) cc = 5;
  const float* lpr = Lbuf + (size_t)bc * 48 + cc * 8;
  float4 La = *(const float4*)lpr;
  float2 Lb = *(const float2*)(lpr + 4);
  float Lc[6] = {La.x, La.y, La.z, La.w, Lb.x, Lb.y};

  float x0c[6];
  {
    const float* xb = gx + (size_t)bc * 6;
    float2 t0 = *(const float2*)(xb);
    float2 t1 = *(const float2*)(xb + 2);
    float2 t2 = *(const float2*)(xb + 4);
    x0c[0]=t0.x; x0c[1]=t0.y; x0c[2]=t1.x; x0c[3]=t1.y; x0c[4]=t2.x; x0c[5]=t2.y;
  }
  float2 uu = *(const float2*)(gu + (size_t)bc * 2);
  unsigned uu_pk = pk2(uu.x, uu.y);

  const char* wp = ws + lane * 96;
  bf16x8 A1v0 = *((const bf16x8*)wp);
  bf16x8 A1v1 = *((const bf16x8*)(wp + 16));
  bf16x8 A2v[4];
#pragma unroll
  for (int kq = 0; kq < 4; ++kq) A2v[kq] = *((const bf16x8*)(wp + 32 + kq * 16));
  float b2r[6];
#pragma unroll
  for (int i = 0; i < 6; ++i) b2r[i] = gb2[i];

  // xs (stage-0 input); fold b2 into bases
  float xs[6], sgnLp[6], xs005[6];
#pragma unroll
  for (int f = 0; f < 6; ++f) {
    float sl = sgn * Lc[f];
    xs[f] = x0c[f] + sl;
    sgnLp[f] = fmaf(0.01f, b2r[f], sl);           // dl base: sgnL + dt*b2
  }
  union { bf16x8 v; unsigned w[4]; } bx;
  bx.w[0] = u ? 0x00003F80u : pk2t(xs[0], xs[1]);
  bx.w[1] = pk2t(xs[2], xs[3]);
  bx.w[2] = pk2t(xs[4], xs[5]);
  bx.w[3] = uu_pk;
#pragma unroll
  for (int f = 0; f < 6; ++f) xs005[f] = fmaf(0.005f, b2r[f], xs[f]);

  f32x16 z16;
#pragma unroll
  for (int i = 0; i < 16; ++i) z16[i] = 0.0f;

  float ksum[6] = {0.f, 0.f, 0.f, 0.f, 0.f, 0.f};
#pragma unroll
  for (int st = 0; st < 4; ++st) {
    f32x16 d1a = __builtin_amdgcn_mfma_f32_32x32x16_bf16(A1v0, bx.v, z16, 0, 0, 0);
    f32x16 d1b = __builtin_amdgcn_mfma_f32_32x32x16_bf16(A1v1, bx.v, z16, 0, 0, 0);
    unsigned Hpk[16];
#pragma unroll
    for (int pr = 0; pr < 8; ++pr) Hpk[pr]     = tanh2_pk(d1a[2*pr], d1a[2*pr+1]);
#pragma unroll
    for (int pr = 0; pr < 8; ++pr) Hpk[8 + pr] = tanh2_pk(d1b[2*pr], d1b[2*pr+1]);
    // layer2: B-fragment = own Hpk[4kq..4kq+3]; A has duplicated feat rows
    f32x16 d2 = z16;
#pragma unroll
    for (int kq = 0; kq < 4; ++kq) {
      union { bf16x8 v; unsigned w[4]; } bh;
      bh.w[0] = Hpk[4*kq+0]; bh.w[1] = Hpk[4*kq+1];
      bh.w[2] = Hpk[4*kq+2]; bh.w[3] = Hpk[4*kq+3];
      d2 = __builtin_amdgcn_mfma_f32_32x32x16_bf16(A2v[kq], bh.v, d2, 0, 0, 0);
    }
    const float wks = (st == 0 || st == 3) ? 1.0f : 2.0f;
#pragma unroll
    for (int f = 0; f < 6; ++f) ksum[f] = fmaf(wks, d2[f], ksum[f]);
    if (st < 3) {
      const float cin = (st == 2) ? 0.01f : 0.005f;
      float xi[6];
#pragma unroll
      for (int f = 0; f < 6; ++f) {
        float basef = (st == 2) ? fmaf(0.005f, b2r[f], xs005[f]) : xs005[f];
        xi[f] = fmaf(cin, d2[f], basef);
      }
      bx.w[0] = u ? 0x00003F80u : pk2t(xi[0], xi[1]);
      bx.w[1] = pk2t(xi[2], xi[3]);
      bx.w[2] = pk2t(xi[4], xi[5]);
    }
  }

  // deltas -> LDS (stride 17, conflict-free); both halves identical, u==0 writes
  const float dt6 = 0.01f / 6.0f;
  if (u == 0) {
#pragma unroll
    for (int f = 0; f < 6; ++f) dxs[c * 17 + f] = fmaf(dt6, ksum[f], sgnLp[f]);
  }

  // ---- moments: two 16x16x32 MFMAs, shared B = dx ----
  float dxv[8];
#pragma unroll
  for (int j = 0; j < 8; ++j) dxv[j] = dxs[(8 * q16 + j) * 17 + m16];
  float wc0[8], wc1[8];
#pragma unroll
  for (int j = 0; j < 8; ++j) {
    float c0j = (j == 0) ? -0.25f : ONE3;
    float c1j = (j <= 4) ? ONE3 : 0.0f;
    wc0[j] = (q16 == 0) ? c0j : ((q16 == 1) ? c1j : 0.0f);
    wc1[j] = (q16 == 2) ? c0j : ((q16 == 3) ? c1j : 0.0f);
  }
  float wm00 = (q16 == 0) ? -3.0f : wc0[0];
  float wm10 = (q16 == 2) ? -3.0f : wc1[0];
  bool mlt6 = (m16 < 6), m6 = (m16 == 6), m7 = (m16 == 7);
  union { bf16x8 v; unsigned w[4]; } am0, am1, bw;
  {
    float a0[8], a1[8];
#pragma unroll
    for (int j = 0; j < 8; ++j) {
      float wmj0 = (j == 0) ? wm00 : wc0[j];
      float wmj1 = (j == 0) ? wm10 : wc1[j];
      float alt0 = m6 ? wc0[j] : (m7 ? wmj0 : 0.0f);
      float alt1 = m6 ? wc1[j] : (m7 ? wmj1 : 0.0f);
      a0[j] = mlt6 ? wc0[j] * dxv[j] : alt0;
      a1[j] = mlt6 ? wc1[j] * dxv[j] : alt1;
    }
#pragma unroll
    for (int pr = 0; pr < 4; ++pr) {
      am0.w[pr] = pk2(a0[2*pr], a0[2*pr+1]);
      am1.w[pr] = pk2(a1[2*pr], a1[2*pr+1]);
      bw.w[pr]  = pk2(dxv[2*pr], dxv[2*pr+1]);
    }
  }
  f32x4 zz = {0.0f, 0.0f, 0.0f, 0.0f};
  f32x4 Dm0 = __builtin_amdgcn_mfma_f32_16x16x32_bf16(am0.v, bw.v, zz, 0, 0, 0);
  f32x4 Dm1 = __builtin_amdgcn_mfma_f32_16x16x32_bf16(am1.v, bw.v, zz, 0, 0, 0);

  if (q16 < 2 && m16 < 6) {
    float* u0 = Ubuf + (size_t)(2 * p) * 48;
    float* u1 = Ubuf + (size_t)(2 * p + 1) * 48;
#pragma unroll
    for (int i = 0; i < 4; ++i) {
      u0[(4 * q16 + i) * 6 + m16] = Dm0[i];
      u1[(4 * q16 + i) * 6 + m16] = Dm1[i];
    }
  }
}

// ---- epilogue: 1 thread/batch; float4-ized memory traffic ----
__global__ void ukf_epi(const float* __restrict__ gx,
                        const float* __restrict__ gy,
                        const char*  __restrict__ ws,
                        const float* __restrict__ Ubuf,
                        float* __restrict__ out, int B) {
  int b = blockIdx.x * blockDim.x + threadIdx.x;
  if (b >= B) return;
  // Ubuf record: 192 B, 16 B aligned -> 12 float4 loads
  float rr[48];
  {
    const float4* r4 = (const float4*)(Ubuf + (size_t)b * 48);
#pragma unroll
    for (int k = 0; k < 12; ++k) {
      float4 v = r4[k];
      rr[4*k+0]=v.x; rr[4*k+1]=v.y; rr[4*k+2]=v.z; rr[4*k+3]=v.w;
    }
  }
  float U[21], cbv[6], dbv[6];
#pragma unroll
  for (int i = 0; i < 6; ++i)
#pragma unroll
    for (int j = 0; j <= i; ++j) U[TRI(i,j)] = rr[i * 6 + j];
#pragma unroll
  for (int j = 0; j < 6; ++j) { cbv[j] = rr[36 + j]; dbv[j] = rr[42 + j]; }

  float x0[6];
  {
    const float* xb = gx + (size_t)b * 6;
    float2 t0 = *(const float2*)(xb);
    float2 t1 = *(const float2*)(xb + 2);
    float2 t2 = *(const float2*)(xb + 4);
    x0[0]=t0.x; x0[1]=t0.y; x0[2]=t1.x; x0[3]=t1.y; x0[4]=t2.x; x0[5]=t2.y;
  }
  const float* yb = gy + (size_t)b * 3;
  float yy0 = yb[0], yy1 = yb[1], yy2 = yb[2];

  const float* qro = (const float*)(ws + QOFF);
  float Qm[21], Rm[6];
#pragma unroll
  for (int t = 0; t < 21; ++t) Qm[t] = qro[t];
#pragma unroll
  for (int t = 0; t < 6; ++t) Rm[t] = qro[21 + t];

  float xp[6];
#pragma unroll
  for (int i = 0; i < 6; ++i) xp[i] = x0[i] + dbv[i];
  float D[21];
#pragma unroll
  for (int i = 0; i < 6; ++i)
#pragma unroll
    for (int j = 0; j <= i; ++j) {
      float v = U[TRI(i,j)];
      v -= cbv[i] * dbv[j];
      v -= dbv[i] * cbv[j];
      v = fmaf(3.75f * dbv[i], dbv[j], v);
      D[TRI(i,j)] = v;
    }
  float s00 = D[TRI(0,0)] + Rm[TRI(0,0)];
  float s10 = D[TRI(1,0)] + Rm[TRI(1,0)];
  float s11 = D[TRI(1,1)] + Rm[TRI(1,1)];
  float s20 = D[TRI(2,0)] + Rm[TRI(2,0)];
  float s21 = D[TRI(2,1)] + Rm[TRI(2,1)];
  float s22 = D[TRI(2,2)] + Rm[TRI(2,2)];
  float a00 = s00 + 1e-5f, a11 = s11 + 1e-5f, a22 = s22 + 1e-5f;
  float a10 = s10, a20 = s20, a21 = s21;
  float adj00 = a11*a22 - a21*a21;
  float adj01 = a20*a21 - a10*a22;
  float adj02 = a10*a21 - a11*a20;
  float adj11 = a00*a22 - a20*a20;
  float adj12 = a10*a20 - a00*a21;
  float adj22 = a00*a11 - a10*a10;
  float det  = a00*adj00 + a10*adj01 + a20*adj02;
  float idet = __builtin_amdgcn_rcpf(det);
  float I00 = adj00*idet, I01 = adj01*idet, I02 = adj02*idet;
  float I11 = adj11*idet, I12 = adj12*idet, I22 = adj22*idet;

#define DS(i,j) ((i) >= (j) ? D[TRI(i,j)] : D[TRI(j,i)])
  float K_[18];
#pragma unroll
  for (int i = 0; i < 6; ++i) {
    float c0 = DS(i,0), c1 = DS(i,1), c2 = DS(i,2);
    K_[i*3+0] = c0*I00 + c1*I01 + c2*I02;
    K_[i*3+1] = c0*I01 + c1*I11 + c2*I12;
    K_[i*3+2] = c0*I02 + c1*I12 + c2*I22;
  }
  float inn0 = yy0 - xp[0], inn1 = yy1 - xp[1], inn2 = yy2 - xp[2];
  float xu[6];
#pragma unroll
  for (int i = 0; i < 6; ++i)
    xu[i] = xp[i] + K_[i*3]*inn0 + K_[i*3+1]*inn1 + K_[i*3+2]*inn2;

  float KS[18];
#pragma unroll
  for (int i = 0; i < 6; ++i) {
    float k0 = K_[i*3], k1 = K_[i*3+1], k2 = K_[i*3+2];
    KS[i*3+0] = k0*s00 + k1*s10 + k2*s20;
    KS[i*3+1] = k0*s10 + k1*s11 + k2*s21;
    KS[i*3+2] = k0*s20 + k1*s21 + k2*s22;
  }
  float Pu[21];
#pragma unroll
  for (int i = 0; i < 6; ++i)
#pragma unroll
    for (int j = 0; j <= i; ++j) {
      float v = D[TRI(i,j)] + Qm[TRI(i,j)];
      v -= KS[i*3]*K_[j*3] + KS[i*3+1]*K_[j*3+1] + KS[i*3+2]*K_[j*3+2];
      Pu[TRI(i,j)] = v + ((i==j) ? 1e-4f : 0.0f);
    }

  float* o_xu = out;
  float* o_Pu = out + (size_t)6  * B;
  float* o_xp = out + (size_t)42 * B;
  float* o_Pp = out + (size_t)48 * B;
  float* o_yp = out + (size_t)84 * B;
  float* o_S  = out + (size_t)87 * B;
  float* o_K  = out + (size_t)96 * B;
  {
    float* pp = o_xu + (size_t)b * 6;           // 24 B stride: float2-aligned only
    ((float2*)pp)[0] = make_float2(xu[0], xu[1]);
    ((float2*)pp)[1] = make_float2(xu[2], xu[3]);
    ((float2*)pp)[2] = make_float2(xu[4], xu[5]);
  }
  {
    float4* pp = (float4*)(o_Pu + (size_t)b * 36);   // 144 B stride: 16 B aligned
#pragma unroll
    for (int q = 0; q < 9; ++q) {
      int e0 = q*4, e1 = q*4+1, e2 = q*4+2, e3 = q*4+3;
      int i0=e0/6,j0=e0%6, i1=e1/6,j1=e1%6, i2=e2/6,j2=e2%6, i3=e3/6,j3=e3%6;
      pp[q] = make_float4(
        (i0>=j0)?Pu[TRI(i0,j0)]:Pu[TRI(j0,i0)],
        (i1>=j1)?Pu[TRI(i1,j1)]:Pu[TRI(j1,i1)],
        (i2>=j2)?Pu[TRI(i2,j2)]:Pu[TRI(j2,i2)],
        (i3>=j3)?Pu[TRI(i3,j3)]:Pu[TRI(j3,i3)]);
    }
  }
  {
    float* pp = o_xp + (size_t)b * 6;
    ((float2*)pp)[0] = make_float2(xp[0], xp[1]);
    ((float2*)pp)[1] = make_float2(xp[2], xp[3]);
    ((float2*)pp)[2] = make_float2(xp[4], xp[5]);
  }
  {
    float4* pp = (float4*)(o_Pp + (size_t)b * 36);
#pragma unroll
    for (int q = 0; q < 9; ++q) {
      int e0 = q*4, e1 = q*4+1, e2 = q*4+2, e3 = q*4+3;
      int i0=e0/6,j0=e0%6, i1=e1/6,j1=e1%6, i2=e2/6,j2=e2%6, i3=e3/6,j3=e3%6;
      pp[q] = make_float4(
        ((i0>=j0)?D[TRI(i0,j0)]:D[TRI(j0,i0)]) + ((i0>=j0)?Qm[TRI(i0,j0)]:Qm[TRI(j0,i0)]),
        ((i1>=j1)?D[TRI(i1,j1)]:D[TRI(j1,i1)]) + ((i1>=j1)?Qm[TRI(i1,j1)]:Qm[TRI(j1,i1)]),
        ((i2>=j2)?D[TRI(i2,j2)]:D[TRI(j2,i2)]) + ((i2>=j2)?Qm[TRI(i2,j2)]:Qm[TRI(j2,i2)]),
        ((i3>=j3)?D[TRI(i3,j3)]:D[TRI(j3,i3)]) + ((i3>=j3)?Qm[TRI(i3,j3)]:Qm[TRI(j3,i3)]));
    }
  }
  {
    float* pp = o_yp + (size_t)b * 3;           // 12 B stride: scalar only
    pp[0] = xp[0]; pp[1] = xp[1]; pp[2] = xp[2];
  }
  {
    float* pp = o_S + (size_t)b * 9;            // 36 B stride: scalar only
    pp[0]=s00; pp[1]=s10; pp[2]=s20;
    pp[3]=s10; pp[4]=s11; pp[5]=s21;
    pp[6]=s20; pp[7]=s21; pp[8]=s22;
  }
  {
    float* pp = o_K + (size_t)b * 18;           // 72 B stride: float2-aligned
#pragma unroll
    for (int i = 0; i < 9; ++i)
      ((float2*)pp)[i] = make_float2(K_[i*2], K_[i*2+1]);
  }
}

extern "C" void kernel_launch(void* const* d_in, const int* in_sizes, int n_in,
                              void* d_out, int out_size, void* d_ws, size_t ws_size,
                              hipStream_t stream) {
  const float* x  = (const float*)d_in[0];
  const float* P  = (const float*)d_in[1];
  const float* u  = (const float*)d_in[2];
  const float* y  = (const float*)d_in[3];
  const float* LQ = (const float*)d_in[4];
  const float* LR = (const float*)d_in[5];
  const float* W1 = (const float*)d_in[6];
  const float* b1 = (const float*)d_in[7];
  const float* W2 = (const float*)d_in[8];
  const float* b2 = (const float*)d_in[9];
  float* out = (float*)d_out;
  char*  ws  = (char*)d_ws;
  int B = in_sizes[0] / 6;

  float* Lbuf = (float*)(ws + LOFF);
  float* Ubuf = (float*)(ws + LOFF + (size_t)B * 192);

  hipLaunchKernelGGL(prep_kernel, dim3((B + 255) / 256), dim3(256), 0, stream,
                     P, W1, b1, W2, LQ, LR, ws, Lbuf, B);
  hipLaunchKernelGGL(ukf_main, dim3((B + 7) / 8), dim3(256), 0, stream,
                     x, u, b2, (const float*)Lbuf, (const char*)ws, Ubuf, B);
  hipLaunchKernelGGL(ukf_epi, dim3((B + 255) / 256), dim3(256), 0, stream,
                     x, y, (const char*)ws, (const float*)Ubuf, out, B);
}